// Round 5
// baseline (403.383 us; speedup 1.0000x reference)
//
#include <hip/hip_runtime.h>
#include <hip/hip_bf16.h>
#include <cstddef>

#define B_ 16
#define T_ 64
#define N_ 1024
#define D_ 32
#define H_ 64
#define C_ 32
#define O_ 12

typedef __attribute__((ext_vector_type(8))) short bf16x8;
typedef __attribute__((ext_vector_type(4))) float f32x4;
#define MFMA16(a,b,c) __builtin_amdgcn_mfma_f32_16x16x32_bf16(a,b,c,0,0,0)

__device__ __forceinline__ float d_tanhf(float v){ float e = __expf(2.f*v); return 1.f - 2.f/(e + 1.f); }
__device__ __forceinline__ float d_sigmf(float v){ return 1.f/(1.f + __expf(-v)); }
__device__ __forceinline__ short f2bs(float f){
  __hip_bfloat16 h = __float2bfloat16(f);
  union { __hip_bfloat16 b; short s; } u; u.b = h; return u.s;
}
__device__ __forceinline__ unsigned int packbf(float lo, float hi){
  return (unsigned int)(unsigned short)f2bs(lo) | ((unsigned int)(unsigned short)f2bs(hi) << 16);
}

// ---------------- K1: Ubf[b,n,0:64]=bf16(m1), [64:128]=bf16(m2) ----------------
__global__ __launch_bounds__(128) void k_u(const float* __restrict__ x,
    const float* __restrict__ w1, const float* __restrict__ b1,
    const float* __restrict__ w2, const float* __restrict__ b2,
    unsigned short* __restrict__ Ubf)
{
  int row = blockIdx.x;               // b*N + n
  int b = row >> 10, n = row & (N_-1);
  int t = threadIdx.x;
  int hh = t & (H_-1), which = t >> 6;
  __shared__ float xl[D_];
  if (t < D_) xl[t] = x[(((size_t)b*T_ + (T_-1))*N_ + n)*D_ + t];
  __syncthreads();
  const float* w  = which ? w2 : w1;
  const float* bi = which ? b2 : b1;
  float acc = bi[hh];
  #pragma unroll
  for (int d = 0; d < D_; ++d) acc += xl[d] * w[d*H_ + hh];
  Ubf[(size_t)row*128 + which*H_ + hh] = (unsigned short)f2bs(acc);
}

// ---------------- K2: adj = softmax(tanh(S)) via MFMA, exp in registers ----------------
__global__ __launch_bounds__(512, 1) void k_adj(const unsigned short* __restrict__ Ubf,
                                                float* __restrict__ adj)
{
  __shared__ float rsum[2][64];
  int b  = blockIdx.x >> 4;
  int n0 = (blockIdx.x & 15) * 64;
  int tid = threadIdx.x;
  int w = tid >> 6, l = tid & 63;
  int wr = w & 3, wc = w >> 2;
  int l15 = l & 15, lg = l >> 4;
  const unsigned short* Ub = Ubf + (size_t)b*N_*128;

  bf16x8 afr[4];
  #pragma unroll
  for (int kc = 0; kc < 4; ++kc)
    afr[kc] = *reinterpret_cast<const bf16x8*>(Ub + (size_t)(n0 + 16*wr + l15)*128 + 32*kc + 8*lg);

  f32x4 acc[32];
  #pragma unroll
  for (int ct = 0; ct < 32; ++ct) acc[ct] = (f32x4){0.f,0.f,0.f,0.f};

  #pragma unroll
  for (int ct = 0; ct < 32; ++ct) {
    const unsigned short* Um = Ub + (size_t)(512*wc + 16*ct + l15)*128;
    #pragma unroll
    for (int kc = 0; kc < 4; ++kc) {
      int ks = (32*kc + 8*lg + 64) & 127;
      bf16x8 bfr = *reinterpret_cast<const bf16x8*>(Um + ks);
      acc[ct] = MFMA16(afr[kc], bfr, acc[ct]);
    }
  }

  float rs[4] = {0.f,0.f,0.f,0.f};
  #pragma unroll
  for (int ct = 0; ct < 32; ++ct) {
    #pragma unroll
    for (int r = 0; r < 4; ++r) {
      float e = __expf(d_tanhf(acc[ct][r]));
      acc[ct][r] = e;
      rs[r] += e;
    }
  }
  #pragma unroll
  for (int r = 0; r < 4; ++r) {
    float s = rs[r];
    s += __shfl_xor(s, 1); s += __shfl_xor(s, 2);
    s += __shfl_xor(s, 4); s += __shfl_xor(s, 8);
    rs[r] = s;
  }
  if (l15 == 0) {
    #pragma unroll
    for (int r = 0; r < 4; ++r)
      rsum[wc][16*wr + 4*lg + r] = rs[r];
  }
  __syncthreads();
  float inv[4];
  #pragma unroll
  for (int r = 0; r < 4; ++r) {
    int row = 16*wr + 4*lg + r;
    inv[r] = 1.0f / (rsum[0][row] + rsum[1][row]);
  }
  #pragma unroll
  for (int ct = 0; ct < 32; ++ct) {
    #pragma unroll
    for (int r = 0; r < 4; ++r) {
      int n = n0 + 16*wr + 4*lg + r;
      int m = 512*wc + 16*ct + l15;
      adj[((size_t)b*N_ + n)*N_ + m] = acc[ct][r] * inv[r];
    }
  }
}

// ---------------- K2b: adjbf = bf16(adj), coalesced ----------------
__global__ __launch_bounds__(256) void k_cvt(const float* __restrict__ a, unsigned short* __restrict__ o)
{
  size_t i = ((size_t)blockIdx.x*256 + threadIdx.x)*8;
  float4 v0 = *reinterpret_cast<const float4*>(a + i);
  float4 v1 = *reinterpret_cast<const float4*>(a + i + 4);
  uint4 r;
  r.x = packbf(v0.x, v0.y); r.y = packbf(v0.z, v0.w);
  r.z = packbf(v1.x, v1.y); r.w = packbf(v1.z, v1.w);
  *reinterpret_cast<uint4*>(o + i) = r;
}

// ---------------- K3: gated dilated convs, last-position only -> h ----------------
// 512 thr, 16 series/block, 1 series/thread. ic blocked by 4 (float4 LDS reads),
// sliding 3-tap float4 window, weights 3xfloat4 per ic4 per tensor.
__global__ __launch_bounds__(512) void k_conv(const float* __restrict__ x,
    const float* __restrict__ fw1,const float* __restrict__ fb1,const float* __restrict__ gw1,const float* __restrict__ gb1,
    const float* __restrict__ fw2,const float* __restrict__ fb2,const float* __restrict__ gw2,const float* __restrict__ gb2,
    const float* __restrict__ fw3,const float* __restrict__ fb3,const float* __restrict__ gw3,const float* __restrict__ gb3,
    float* __restrict__ h)
{
  __shared__ float xs[16][15][32];   // 30.7 KB
  __shared__ float y1[16][7][32];    // 14.3 KB
  __shared__ float y2[16][3][32];    //  6.1 KB
  int tid = threadIdx.x;
  int b  = blockIdx.x >> 6;
  int n0 = (blockIdx.x & 63) * 16;

  for (int l = tid; l < 1920; l += 512) {
    int t = l >> 7, r = l & 127;
    int nl = r >> 3, d4 = r & 7;
    float4 v = reinterpret_cast<const float4*>(x)[(((size_t)b*T_ + 49 + t)*N_ + n0 + nl)*8 + d4];
    *reinterpret_cast<float4*>(&xs[nl][t][d4*4]) = v;
  }
  __syncthreads();

  int s = tid >> 5, c = tid & 31;

  // ---- conv1 (dil 1), 7 positions
  float af[7], ag[7];
  {
    float bf = fb1[c], bg = gb1[c];
    #pragma unroll
    for (int p=0;p<7;++p){ af[p]=bf; ag[p]=bg; }
  }
  for (int ic4 = 0; ic4 < 8; ++ic4) {
    float wf[12], wg[12];   // [j*3+k], j=ic lane 0..3
    {
      const float4* f4p = reinterpret_cast<const float4*>(fw1) + c*24 + ic4*3;
      const float4* g4p = reinterpret_cast<const float4*>(gw1) + c*24 + ic4*3;
      #pragma unroll
      for (int q=0;q<3;++q){
        float4 a = f4p[q], g = g4p[q];
        wf[q*4+0]=a.x; wf[q*4+1]=a.y; wf[q*4+2]=a.z; wf[q*4+3]=a.w;
        wg[q*4+0]=g.x; wg[q*4+1]=g.y; wg[q*4+2]=g.z; wg[q*4+3]=g.w;
      }
    }
    float4 x0 = *reinterpret_cast<const float4*>(&xs[s][0][ic4*4]);
    float4 x1 = *reinterpret_cast<const float4*>(&xs[s][1][ic4*4]);
    #pragma unroll
    for (int p = 0; p < 7; ++p) {
      float4 x2 = *reinterpret_cast<const float4*>(&xs[s][2*p+2][ic4*4]);
      af[p] += x0.x*wf[0] + x0.y*wf[3] + x0.z*wf[6] + x0.w*wf[9]
             + x1.x*wf[1] + x1.y*wf[4] + x1.z*wf[7] + x1.w*wf[10]
             + x2.x*wf[2] + x2.y*wf[5] + x2.z*wf[8] + x2.w*wf[11];
      ag[p] += x0.x*wg[0] + x0.y*wg[3] + x0.z*wg[6] + x0.w*wg[9]
             + x1.x*wg[1] + x1.y*wg[4] + x1.z*wg[7] + x1.w*wg[10]
             + x2.x*wg[2] + x2.y*wg[5] + x2.z*wg[8] + x2.w*wg[11];
      if (p < 6) { x0 = x2; x1 = *reinterpret_cast<const float4*>(&xs[s][2*p+3][ic4*4]); }
    }
  }
  #pragma unroll
  for (int p=0;p<7;++p) y1[s][p][c] = d_tanhf(af[p]) * d_sigmf(ag[p]);
  __syncthreads();

  // ---- conv2 (dil 2), 3 positions, taps y1[2r+k]
  float af2[3], ag2[3];
  {
    float bf = fb2[c], bg = gb2[c];
    #pragma unroll
    for (int r=0;r<3;++r){ af2[r]=bf; ag2[r]=bg; }
  }
  for (int ic4 = 0; ic4 < 8; ++ic4) {
    float wf[12], wg[12];
    {
      const float4* f4p = reinterpret_cast<const float4*>(fw2) + c*24 + ic4*3;
      const float4* g4p = reinterpret_cast<const float4*>(gw2) + c*24 + ic4*3;
      #pragma unroll
      for (int q=0;q<3;++q){
        float4 a = f4p[q], g = g4p[q];
        wf[q*4+0]=a.x; wf[q*4+1]=a.y; wf[q*4+2]=a.z; wf[q*4+3]=a.w;
        wg[q*4+0]=g.x; wg[q*4+1]=g.y; wg[q*4+2]=g.z; wg[q*4+3]=g.w;
      }
    }
    float4 u0 = *reinterpret_cast<const float4*>(&y1[s][0][ic4*4]);
    float4 u1 = *reinterpret_cast<const float4*>(&y1[s][1][ic4*4]);
    #pragma unroll
    for (int r = 0; r < 3; ++r) {
      float4 u2 = *reinterpret_cast<const float4*>(&y1[s][2*r+2][ic4*4]);
      af2[r] += u0.x*wf[0] + u0.y*wf[3] + u0.z*wf[6] + u0.w*wf[9]
              + u1.x*wf[1] + u1.y*wf[4] + u1.z*wf[7] + u1.w*wf[10]
              + u2.x*wf[2] + u2.y*wf[5] + u2.z*wf[8] + u2.w*wf[11];
      ag2[r] += u0.x*wg[0] + u0.y*wg[3] + u0.z*wg[6] + u0.w*wg[9]
              + u1.x*wg[1] + u1.y*wg[4] + u1.z*wg[7] + u1.w*wg[10]
              + u2.x*wg[2] + u2.y*wg[5] + u2.z*wg[8] + u2.w*wg[11];
      if (r < 2) { u0 = u2; u1 = *reinterpret_cast<const float4*>(&y1[s][2*r+3][ic4*4]); }
    }
  }
  #pragma unroll
  for (int r=0;r<3;++r) y2[s][r][c] = d_tanhf(af2[r]) * d_sigmf(ag2[r]);
  __syncthreads();

  // ---- conv3 (dil 4), last position, taps y2[k]
  float af3 = fb3[c], ag3 = gb3[c];
  for (int ic4 = 0; ic4 < 8; ++ic4) {
    float wf[12], wg[12];
    {
      const float4* f4p = reinterpret_cast<const float4*>(fw3) + c*24 + ic4*3;
      const float4* g4p = reinterpret_cast<const float4*>(gw3) + c*24 + ic4*3;
      #pragma unroll
      for (int q=0;q<3;++q){
        float4 a = f4p[q], g = g4p[q];
        wf[q*4+0]=a.x; wf[q*4+1]=a.y; wf[q*4+2]=a.z; wf[q*4+3]=a.w;
        wg[q*4+0]=g.x; wg[q*4+1]=g.y; wg[q*4+2]=g.z; wg[q*4+3]=g.w;
      }
    }
    float4 v0 = *reinterpret_cast<const float4*>(&y2[s][0][ic4*4]);
    float4 v1 = *reinterpret_cast<const float4*>(&y2[s][1][ic4*4]);
    float4 v2 = *reinterpret_cast<const float4*>(&y2[s][2][ic4*4]);
    af3 += v0.x*wf[0] + v0.y*wf[3] + v0.z*wf[6] + v0.w*wf[9]
         + v1.x*wf[1] + v1.y*wf[4] + v1.z*wf[7] + v1.w*wf[10]
         + v2.x*wf[2] + v2.y*wf[5] + v2.z*wf[8] + v2.w*wf[11];
    ag3 += v0.x*wg[0] + v0.y*wg[3] + v0.z*wg[6] + v0.w*wg[9]
         + v1.x*wg[1] + v1.y*wg[4] + v1.z*wg[7] + v1.w*wg[10]
         + v2.x*wg[2] + v2.y*wg[5] + v2.z*wg[8] + v2.w*wg[11];
  }
  h[((size_t)b*N_ + n0 + s)*C_ + c] = d_tanhf(af3) * d_sigmf(ag3);
}

// ---------------- K3b: zbT0[b][c][n] = bf16(h[b][n][c]) ----------------
__global__ __launch_bounds__(256) void k_zb(const float* __restrict__ h, unsigned short* __restrict__ zbT)
{
  __shared__ float t[32][33];
  int b = blockIdx.x >> 5, n0 = (blockIdx.x & 31) * 32;
  int tid = threadIdx.x;
  {
    int r = tid >> 3, c4 = tid & 7;
    float4 v = reinterpret_cast<const float4*>(h + ((size_t)b*N_ + n0 + r)*32)[c4];
    t[r][c4*4+0]=v.x; t[r][c4*4+1]=v.y; t[r][c4*4+2]=v.z; t[r][c4*4+3]=v.w;
  }
  __syncthreads();
  int c = tid >> 3, ng = (tid & 7) * 4;
  uint2 val;
  val.x = packbf(t[ng+0][c], t[ng+1][c]);
  val.y = packbf(t[ng+2][c], t[ng+3][c]);
  *reinterpret_cast<uint2*>(zbT + ((size_t)b*32 + c)*N_ + n0 + ng) = val;
}

// ---------------- K4: z' = 0.1h + 0.45z + 0.45 adj@z via MFMA (bf16 adj) ----------------
__global__ __launch_bounds__(256) void k_propm_bf(const unsigned short* __restrict__ adjbf,
    const unsigned short* __restrict__ zbT, const float* __restrict__ h,
    const float* __restrict__ zin, float* __restrict__ zout,
    unsigned short* __restrict__ zbTout)
{
  int b = blockIdx.x >> 5;
  int g = blockIdx.x & 31;
  int tid = threadIdx.x;
  int w = tid >> 6, l = tid & 63;
  int wr = w >> 1, wc = w & 1;
  int l15 = l & 15, lg = l >> 4;
  int n_base = g*32 + 16*wr;

  const unsigned short* A = adjbf + ((size_t)b*N_ + n_base + l15)*N_;
  const unsigned short* Z = zbT + ((size_t)b*32 + 16*wc + l15)*N_;

  f32x4 acc = {0.f,0.f,0.f,0.f};
  #pragma unroll 8
  for (int kc = 0; kc < 32; ++kc) {
    int k0 = 32*kc + 8*lg;
    bf16x8 afr = *reinterpret_cast<const bf16x8*>(A + k0);
    bf16x8 bfr = *reinterpret_cast<const bf16x8*>(Z + k0);
    acc = MFMA16(afr, bfr, acc);
  }

  int c = 16*wc + l15;
  #pragma unroll
  for (int r = 0; r < 4; ++r) {
    int n = n_base + 4*lg + r;
    size_t idx = ((size_t)b*N_ + n)*32 + c;
    float v = 0.1f*h[idx] + 0.45f*zin[idx] + 0.45f*acc[r];
    zout[idx] = v;
    zbTout[((size_t)b*32 + c)*N_ + n] = (unsigned short)f2bs(v);
  }
}

// ---------------- K4 fallback: fp32 adj with on-the-fly cvt ----------------
__global__ __launch_bounds__(256) void k_propm_f32(const float* __restrict__ adj,
    const unsigned short* __restrict__ zbT, const float* __restrict__ h,
    const float* __restrict__ zin, float* __restrict__ zout,
    unsigned short* __restrict__ zbTout)
{
  int b = blockIdx.x >> 5;
  int g = blockIdx.x & 31;
  int tid = threadIdx.x;
  int w = tid >> 6, l = tid & 63;
  int wr = w >> 1, wc = w & 1;
  int l15 = l & 15, lg = l >> 4;
  int n_base = g*32 + 16*wr;

  const float* A = adj + ((size_t)b*N_ + n_base + l15)*N_;
  const unsigned short* Z = zbT + ((size_t)b*32 + 16*wc + l15)*N_;

  f32x4 acc = {0.f,0.f,0.f,0.f};
  #pragma unroll 8
  for (int kc = 0; kc < 32; ++kc) {
    int k0 = 32*kc + 8*lg;
    f32x4 a0 = *reinterpret_cast<const f32x4*>(A + k0);
    f32x4 a1 = *reinterpret_cast<const f32x4*>(A + k0 + 4);
    bf16x8 bfr = *reinterpret_cast<const bf16x8*>(Z + k0);
    bf16x8 afr;
    afr[0]=f2bs(a0[0]); afr[1]=f2bs(a0[1]); afr[2]=f2bs(a0[2]); afr[3]=f2bs(a0[3]);
    afr[4]=f2bs(a1[0]); afr[5]=f2bs(a1[1]); afr[6]=f2bs(a1[2]); afr[7]=f2bs(a1[3]);
    acc = MFMA16(afr, bfr, acc);
  }

  int c = 16*wc + l15;
  #pragma unroll
  for (int r = 0; r < 4; ++r) {
    int n = n_base + 4*lg + r;
    size_t idx = ((size_t)b*N_ + n)*32 + c;
    float v = 0.1f*h[idx] + 0.45f*zin[idx] + 0.45f*acc[r];
    zout[idx] = v;
    zbTout[((size_t)b*32 + c)*N_ + n] = (unsigned short)f2bs(v);
  }
}

// ---------------- K5: out = relu(z) @ wo + bo ----------------
__global__ __launch_bounds__(256) void k_out(const float* __restrict__ z, const float* __restrict__ wo,
                                             const float* __restrict__ bo, float* __restrict__ out)
{
  int gid = blockIdx.x*256 + threadIdx.x;
  if (gid >= B_*N_*O_) return;
  int o = gid % O_; int row = gid / O_;
  const float* zr = z + (size_t)row*C_;
  float acc = bo[o];
  #pragma unroll
  for (int cc = 0; cc < C_; ++cc) acc += fmaxf(zr[cc], 0.f) * wo[cc*O_ + o];
  out[gid] = acc;
}

extern "C" void kernel_launch(void* const* d_in, const int* in_sizes, int n_in,
                              void* d_out, int out_size, void* d_ws, size_t ws_size,
                              hipStream_t stream)
{
  const float* x   = (const float*)d_in[0];
  const float* w1  = (const float*)d_in[1];
  const float* b1  = (const float*)d_in[2];
  const float* w2  = (const float*)d_in[3];
  const float* b2  = (const float*)d_in[4];
  const float* fw1 = (const float*)d_in[5];  const float* fb1 = (const float*)d_in[6];
  const float* gw1 = (const float*)d_in[7];  const float* gb1 = (const float*)d_in[8];
  const float* fw2 = (const float*)d_in[9];  const float* fb2 = (const float*)d_in[10];
  const float* gw2 = (const float*)d_in[11]; const float* gb2 = (const float*)d_in[12];
  const float* fw3 = (const float*)d_in[13]; const float* fb3 = (const float*)d_in[14];
  const float* gw3 = (const float*)d_in[15]; const float* gb3 = (const float*)d_in[16];
  const float* wo  = (const float*)d_in[17]; const float* bo  = (const float*)d_in[18];

  float* out = (float*)d_out;
  float* adj = out + (size_t)B_*N_*O_;

  char* ws = (char*)d_ws;
  unsigned short* Ubf  = (unsigned short*)ws;                       // 4 MB
  float* h             = (float*)(ws + (4ull<<20));                 // 2 MB
  float* z0            = (float*)(ws + (6ull<<20));                 // 2 MB
  float* z1            = (float*)(ws + (8ull<<20));                 // 2 MB
  unsigned short* zbT0 = (unsigned short*)(ws + (10ull<<20));       // 1 MB
  unsigned short* zbT1 = (unsigned short*)(ws + (11ull<<20));       // 1 MB
  unsigned short* adjbf= (unsigned short*)(ws + (12ull<<20));       // 32 MB
  bool use_bf = ws_size >= (44ull<<20);

  k_u<<<B_*N_, 128, 0, stream>>>(x, w1, b1, w2, b2, Ubf);
  k_adj<<<B_*16, 512, 0, stream>>>(Ubf, adj);
  if (use_bf)
    k_cvt<<<B_*N_*N_/8/256, 256, 0, stream>>>(adj, adjbf);
  k_conv<<<B_*N_/16, 512, 0, stream>>>(x, fw1,fb1,gw1,gb1, fw2,fb2,gw2,gb2, fw3,fb3,gw3,gb3, h);
  k_zb<<<B_*32, 256, 0, stream>>>(h, zbT0);

  const float* zi = h;
  const unsigned short* zbi = zbT0;
  float* zfbuf[2] = {z0, z1};
  unsigned short* zbbuf[2] = {zbT1, zbT0};
  for (int it = 0; it < 10; ++it) {
    float* zo = zfbuf[it & 1];
    unsigned short* zbo = zbbuf[it & 1];
    if (use_bf)
      k_propm_bf<<<B_*32, 256, 0, stream>>>(adjbf, zbi, h, zi, zo, zbo);
    else
      k_propm_f32<<<B_*32, 256, 0, stream>>>(adj, zbi, h, zi, zo, zbo);
    zi = zo; zbi = zbo;
  }
  k_out<<<(B_*N_*O_ + 255)/256, 256, 0, stream>>>(zi, wo, bo, out);
}

// Round 6
// 376.704 us; speedup vs baseline: 1.0708x; 1.0708x over previous
//
#include <hip/hip_runtime.h>
#include <hip/hip_bf16.h>
#include <cstddef>

#define B_ 16
#define T_ 64
#define N_ 1024
#define D_ 32
#define H_ 64
#define C_ 32
#define O_ 12

typedef __attribute__((ext_vector_type(8))) short bf16x8;
typedef __attribute__((ext_vector_type(4))) float f32x4;
#define MFMA16(a,b,c) __builtin_amdgcn_mfma_f32_16x16x32_bf16(a,b,c,0,0,0)

__device__ __forceinline__ float d_tanhf(float v){ float e = __expf(2.f*v); return 1.f - 2.f/(e + 1.f); }
__device__ __forceinline__ float d_sigmf(float v){ return 1.f/(1.f + __expf(-v)); }
__device__ __forceinline__ short f2bs(float f){
  __hip_bfloat16 h = __float2bfloat16(f);
  union { __hip_bfloat16 b; short s; } u; u.b = h; return u.s;
}

// ---------------- K1: Ubf[b,n,0:64]=bf16(m1), [64:128]=bf16(m2) ----------------
__global__ __launch_bounds__(128) void k_u(const float* __restrict__ x,
    const float* __restrict__ w1, const float* __restrict__ b1,
    const float* __restrict__ w2, const float* __restrict__ b2,
    unsigned short* __restrict__ Ubf)
{
  int row = blockIdx.x;               // b*N + n
  int b = row >> 10, n = row & (N_-1);
  int t = threadIdx.x;
  int hh = t & (H_-1), which = t >> 6;
  __shared__ float xl[D_];
  if (t < D_) xl[t] = x[(((size_t)b*T_ + (T_-1))*N_ + n)*D_ + t];
  __syncthreads();
  const float* w  = which ? w2 : w1;
  const float* bi = which ? b2 : b1;
  float acc = bi[hh];
  #pragma unroll
  for (int d = 0; d < D_; ++d) acc += xl[d] * w[d*H_ + hh];
  Ubf[(size_t)row*128 + which*H_ + hh] = (unsigned short)f2bs(acc);
}

// ---------------- K2: adj = softmax(tanh(S)) via MFMA; also emits bf16 copy ----------------
__global__ __launch_bounds__(512, 1) void k_adj(const unsigned short* __restrict__ Ubf,
                                                float* __restrict__ adj,
                                                unsigned short* __restrict__ adjbf,
                                                int write_bf)
{
  __shared__ float rsum[2][64];
  int b  = blockIdx.x >> 4;
  int n0 = (blockIdx.x & 15) * 64;
  int tid = threadIdx.x;
  int w = tid >> 6, l = tid & 63;
  int wr = w & 3, wc = w >> 2;
  int l15 = l & 15, lg = l >> 4;
  const unsigned short* Ub = Ubf + (size_t)b*N_*128;

  bf16x8 afr[4];
  #pragma unroll
  for (int kc = 0; kc < 4; ++kc)
    afr[kc] = *reinterpret_cast<const bf16x8*>(Ub + (size_t)(n0 + 16*wr + l15)*128 + 32*kc + 8*lg);

  f32x4 acc[32];
  #pragma unroll
  for (int ct = 0; ct < 32; ++ct) acc[ct] = (f32x4){0.f,0.f,0.f,0.f};

  #pragma unroll
  for (int ct = 0; ct < 32; ++ct) {
    const unsigned short* Um = Ub + (size_t)(512*wc + 16*ct + l15)*128;
    #pragma unroll
    for (int kc = 0; kc < 4; ++kc) {
      int ks = (32*kc + 8*lg + 64) & 127;
      bf16x8 bfr = *reinterpret_cast<const bf16x8*>(Um + ks);
      acc[ct] = MFMA16(afr[kc], bfr, acc[ct]);
    }
  }

  float rs[4] = {0.f,0.f,0.f,0.f};
  #pragma unroll
  for (int ct = 0; ct < 32; ++ct) {
    #pragma unroll
    for (int r = 0; r < 4; ++r) {
      float e = __expf(d_tanhf(acc[ct][r]));
      acc[ct][r] = e;
      rs[r] += e;
    }
  }
  #pragma unroll
  for (int r = 0; r < 4; ++r) {
    float s = rs[r];
    s += __shfl_xor(s, 1); s += __shfl_xor(s, 2);
    s += __shfl_xor(s, 4); s += __shfl_xor(s, 8);
    rs[r] = s;
  }
  if (l15 == 0) {
    #pragma unroll
    for (int r = 0; r < 4; ++r)
      rsum[wc][16*wr + 4*lg + r] = rs[r];
  }
  __syncthreads();
  float inv[4];
  #pragma unroll
  for (int r = 0; r < 4; ++r) {
    int row = 16*wr + 4*lg + r;
    inv[r] = 1.0f / (rsum[0][row] + rsum[1][row]);
  }
  #pragma unroll
  for (int ct = 0; ct < 32; ++ct) {
    #pragma unroll
    for (int r = 0; r < 4; ++r) {
      int n = n0 + 16*wr + 4*lg + r;
      int m = 512*wc + 16*ct + l15;
      float v = acc[ct][r] * inv[r];
      size_t idx = ((size_t)b*N_ + n)*N_ + m;
      adj[idx] = v;
      if (write_bf) adjbf[idx] = (unsigned short)f2bs(v);
    }
  }
}

// ---------------- K3: gated dilated convs, last position -> h (+ bf16 transposed zbT) ----------------
// 256 thr, 8 series/block, 1 series/thread. Direct per-tap float4 LDS reads.
__global__ __launch_bounds__(256) void k_conv(const float* __restrict__ x,
    const float* __restrict__ fw1,const float* __restrict__ fb1,const float* __restrict__ gw1,const float* __restrict__ gb1,
    const float* __restrict__ fw2,const float* __restrict__ fb2,const float* __restrict__ gw2,const float* __restrict__ gb2,
    const float* __restrict__ fw3,const float* __restrict__ fb3,const float* __restrict__ gw3,const float* __restrict__ gb3,
    float* __restrict__ h, unsigned short* __restrict__ zbT)
{
  __shared__ float xs[8][15][32];   // 15.4 KB
  __shared__ float y1[8][7][32];    //  7.2 KB
  __shared__ float y2[8][3][32];    //  3.1 KB
  int tid = threadIdx.x;
  int b  = blockIdx.x >> 7;
  int n0 = (blockIdx.x & 127) * 8;

  for (int l = tid; l < 960; l += 256) {
    int t = l >> 6, r = l & 63;
    int nl = r >> 3, d4 = r & 7;
    float4 v = reinterpret_cast<const float4*>(x)[(((size_t)b*T_ + 49 + t)*N_ + n0 + nl)*8 + d4];
    *reinterpret_cast<float4*>(&xs[nl][t][d4*4]) = v;
  }
  __syncthreads();

  int s = tid >> 5, c = tid & 31;

  // ---- conv1 (dil 1), 7 positions
  float af[7], ag[7];
  {
    float bf = fb1[c], bg = gb1[c];
    #pragma unroll
    for (int p=0;p<7;++p){ af[p]=bf; ag[p]=bg; }
  }
  for (int ic4 = 0; ic4 < 8; ++ic4) {
    float wfl[12], wgl[12];
    {
      const float4* f4p = reinterpret_cast<const float4*>(fw1) + c*24 + ic4*3;
      const float4* g4p = reinterpret_cast<const float4*>(gw1) + c*24 + ic4*3;
      #pragma unroll
      for (int q=0;q<3;++q){
        float4 a = f4p[q], g = g4p[q];
        wfl[q*4+0]=a.x; wfl[q*4+1]=a.y; wfl[q*4+2]=a.z; wfl[q*4+3]=a.w;
        wgl[q*4+0]=g.x; wgl[q*4+1]=g.y; wgl[q*4+2]=g.z; wgl[q*4+3]=g.w;
      }
    }
    #pragma unroll
    for (int p = 0; p < 7; ++p) {
      float4 xa = *reinterpret_cast<const float4*>(&xs[s][2*p+0][ic4*4]);
      float4 xb = *reinterpret_cast<const float4*>(&xs[s][2*p+1][ic4*4]);
      float4 xc = *reinterpret_cast<const float4*>(&xs[s][2*p+2][ic4*4]);
      af[p] += xa.x*wfl[0] + xb.x*wfl[1] + xc.x*wfl[2]
             + xa.y*wfl[3] + xb.y*wfl[4] + xc.y*wfl[5]
             + xa.z*wfl[6] + xb.z*wfl[7] + xc.z*wfl[8]
             + xa.w*wfl[9] + xb.w*wfl[10]+ xc.w*wfl[11];
      ag[p] += xa.x*wgl[0] + xb.x*wgl[1] + xc.x*wgl[2]
             + xa.y*wgl[3] + xb.y*wgl[4] + xc.y*wgl[5]
             + xa.z*wgl[6] + xb.z*wgl[7] + xc.z*wgl[8]
             + xa.w*wgl[9] + xb.w*wgl[10]+ xc.w*wgl[11];
    }
  }
  #pragma unroll
  for (int p=0;p<7;++p) y1[s][p][c] = d_tanhf(af[p]) * d_sigmf(ag[p]);
  __syncthreads();

  // ---- conv2 (dil 2), 3 positions
  float af2[3], ag2[3];
  {
    float bf = fb2[c], bg = gb2[c];
    #pragma unroll
    for (int r=0;r<3;++r){ af2[r]=bf; ag2[r]=bg; }
  }
  for (int ic4 = 0; ic4 < 8; ++ic4) {
    float wfl[12], wgl[12];
    {
      const float4* f4p = reinterpret_cast<const float4*>(fw2) + c*24 + ic4*3;
      const float4* g4p = reinterpret_cast<const float4*>(gw2) + c*24 + ic4*3;
      #pragma unroll
      for (int q=0;q<3;++q){
        float4 a = f4p[q], g = g4p[q];
        wfl[q*4+0]=a.x; wfl[q*4+1]=a.y; wfl[q*4+2]=a.z; wfl[q*4+3]=a.w;
        wgl[q*4+0]=g.x; wgl[q*4+1]=g.y; wgl[q*4+2]=g.z; wgl[q*4+3]=g.w;
      }
    }
    #pragma unroll
    for (int r = 0; r < 3; ++r) {
      float4 xa = *reinterpret_cast<const float4*>(&y1[s][2*r+0][ic4*4]);
      float4 xb = *reinterpret_cast<const float4*>(&y1[s][2*r+1][ic4*4]);
      float4 xc = *reinterpret_cast<const float4*>(&y1[s][2*r+2][ic4*4]);
      af2[r] += xa.x*wfl[0] + xb.x*wfl[1] + xc.x*wfl[2]
              + xa.y*wfl[3] + xb.y*wfl[4] + xc.y*wfl[5]
              + xa.z*wfl[6] + xb.z*wfl[7] + xc.z*wfl[8]
              + xa.w*wfl[9] + xb.w*wfl[10]+ xc.w*wfl[11];
      ag2[r] += xa.x*wgl[0] + xb.x*wgl[1] + xc.x*wgl[2]
              + xa.y*wgl[3] + xb.y*wgl[4] + xc.y*wgl[5]
              + xa.z*wgl[6] + xb.z*wgl[7] + xc.z*wgl[8]
              + xa.w*wgl[9] + xb.w*wgl[10]+ xc.w*wgl[11];
    }
  }
  #pragma unroll
  for (int r=0;r<3;++r) y2[s][r][c] = d_tanhf(af2[r]) * d_sigmf(ag2[r]);
  __syncthreads();

  // ---- conv3 (dil 4), last position
  float af3 = fb3[c], ag3 = gb3[c];
  for (int ic4 = 0; ic4 < 8; ++ic4) {
    float wfl[12], wgl[12];
    {
      const float4* f4p = reinterpret_cast<const float4*>(fw3) + c*24 + ic4*3;
      const float4* g4p = reinterpret_cast<const float4*>(gw3) + c*24 + ic4*3;
      #pragma unroll
      for (int q=0;q<3;++q){
        float4 a = f4p[q], g = g4p[q];
        wfl[q*4+0]=a.x; wfl[q*4+1]=a.y; wfl[q*4+2]=a.z; wfl[q*4+3]=a.w;
        wgl[q*4+0]=g.x; wgl[q*4+1]=g.y; wgl[q*4+2]=g.z; wgl[q*4+3]=g.w;
      }
    }
    float4 xa = *reinterpret_cast<const float4*>(&y2[s][0][ic4*4]);
    float4 xb = *reinterpret_cast<const float4*>(&y2[s][1][ic4*4]);
    float4 xc = *reinterpret_cast<const float4*>(&y2[s][2][ic4*4]);
    af3 += xa.x*wfl[0] + xb.x*wfl[1] + xc.x*wfl[2]
         + xa.y*wfl[3] + xb.y*wfl[4] + xc.y*wfl[5]
         + xa.z*wfl[6] + xb.z*wfl[7] + xc.z*wfl[8]
         + xa.w*wfl[9] + xb.w*wfl[10]+ xc.w*wfl[11];
    ag3 += xa.x*wgl[0] + xb.x*wgl[1] + xc.x*wgl[2]
         + xa.y*wgl[3] + xb.y*wgl[4] + xc.y*wgl[5]
         + xa.z*wgl[6] + xb.z*wgl[7] + xc.z*wgl[8]
         + xa.w*wgl[9] + xb.w*wgl[10]+ xc.w*wgl[11];
  }
  float hv = d_tanhf(af3) * d_sigmf(ag3);
  int n = n0 + s;
  h[((size_t)b*N_ + n)*C_ + c] = hv;
  zbT[((size_t)b*32 + c)*N_ + n] = (unsigned short)f2bs(hv);
}

// ---------------- K4: z' = 0.1h + 0.45z + 0.45 adj@z via MFMA (bf16 adj), 2-way K-split ----------------
__global__ __launch_bounds__(256) void k_propm_bf(const unsigned short* __restrict__ adjbf,
    const unsigned short* __restrict__ zbT, const float* __restrict__ h,
    const float* __restrict__ zin, float* __restrict__ zout,
    unsigned short* __restrict__ zbTout)
{
  __shared__ float red[2][16][17];
  int b = blockIdx.x >> 6;
  int g = blockIdx.x & 63;
  int tid = threadIdx.x;
  int w = tid >> 6, l = tid & 63;
  int wk = w >> 1, wc = w & 1;
  int l15 = l & 15, lg = l >> 4;
  int n_base = g*16;

  const unsigned short* A = adjbf + ((size_t)b*N_ + n_base + l15)*N_ + wk*512;
  const unsigned short* Z = zbT + ((size_t)b*32 + 16*wc + l15)*N_ + wk*512;

  f32x4 acc = {0.f,0.f,0.f,0.f};
  #pragma unroll 8
  for (int kc = 0; kc < 16; ++kc) {
    int k0 = 32*kc + 8*lg;
    bf16x8 afr = *reinterpret_cast<const bf16x8*>(A + k0);
    bf16x8 bfr = *reinterpret_cast<const bf16x8*>(Z + k0);
    acc = MFMA16(afr, bfr, acc);
  }

  if (wk == 1) {
    #pragma unroll
    for (int r = 0; r < 4; ++r) red[wc][4*lg + r][l15] = acc[r];
  }
  __syncthreads();
  if (wk == 0) {
    int c = 16*wc + l15;
    #pragma unroll
    for (int r = 0; r < 4; ++r) {
      float a = acc[r] + red[wc][4*lg + r][l15];
      int n = n_base + 4*lg + r;
      size_t idx = ((size_t)b*N_ + n)*32 + c;
      float v = 0.1f*h[idx] + 0.45f*zin[idx] + 0.45f*a;
      zout[idx] = v;
      zbTout[((size_t)b*32 + c)*N_ + n] = (unsigned short)f2bs(v);
    }
  }
}

// ---------------- K4 fallback: fp32 adj with on-the-fly cvt, 2-way K-split ----------------
__global__ __launch_bounds__(256) void k_propm_f32(const float* __restrict__ adj,
    const unsigned short* __restrict__ zbT, const float* __restrict__ h,
    const float* __restrict__ zin, float* __restrict__ zout,
    unsigned short* __restrict__ zbTout)
{
  __shared__ float red[2][16][17];
  int b = blockIdx.x >> 6;
  int g = blockIdx.x & 63;
  int tid = threadIdx.x;
  int w = tid >> 6, l = tid & 63;
  int wk = w >> 1, wc = w & 1;
  int l15 = l & 15, lg = l >> 4;
  int n_base = g*16;

  const float* A = adj + ((size_t)b*N_ + n_base + l15)*N_ + wk*512;
  const unsigned short* Z = zbT + ((size_t)b*32 + 16*wc + l15)*N_ + wk*512;

  f32x4 acc = {0.f,0.f,0.f,0.f};
  #pragma unroll 8
  for (int kc = 0; kc < 16; ++kc) {
    int k0 = 32*kc + 8*lg;
    f32x4 a0 = *reinterpret_cast<const f32x4*>(A + k0);
    f32x4 a1 = *reinterpret_cast<const f32x4*>(A + k0 + 4);
    bf16x8 bfr = *reinterpret_cast<const bf16x8*>(Z + k0);
    bf16x8 afr;
    afr[0]=f2bs(a0[0]); afr[1]=f2bs(a0[1]); afr[2]=f2bs(a0[2]); afr[3]=f2bs(a0[3]);
    afr[4]=f2bs(a1[0]); afr[5]=f2bs(a1[1]); afr[6]=f2bs(a1[2]); afr[7]=f2bs(a1[3]);
    acc = MFMA16(afr, bfr, acc);
  }

  if (wk == 1) {
    #pragma unroll
    for (int r = 0; r < 4; ++r) red[wc][4*lg + r][l15] = acc[r];
  }
  __syncthreads();
  if (wk == 0) {
    int c = 16*wc + l15;
    #pragma unroll
    for (int r = 0; r < 4; ++r) {
      float a = acc[r] + red[wc][4*lg + r][l15];
      int n = n_base + 4*lg + r;
      size_t idx = ((size_t)b*N_ + n)*32 + c;
      float v = 0.1f*h[idx] + 0.45f*zin[idx] + 0.45f*a;
      zout[idx] = v;
      zbTout[((size_t)b*32 + c)*N_ + n] = (unsigned short)f2bs(v);
    }
  }
}

// ---------------- K5: out = relu(z) @ wo + bo ----------------
__global__ __launch_bounds__(256) void k_out(const float* __restrict__ z, const float* __restrict__ wo,
                                             const float* __restrict__ bo, float* __restrict__ out)
{
  int gid = blockIdx.x*256 + threadIdx.x;
  if (gid >= B_*N_*O_) return;
  int o = gid % O_; int row = gid / O_;
  const float* zr = z + (size_t)row*C_;
  float acc = bo[o];
  #pragma unroll
  for (int cc = 0; cc < C_; ++cc) acc += fmaxf(zr[cc], 0.f) * wo[cc*O_ + o];
  out[gid] = acc;
}

extern "C" void kernel_launch(void* const* d_in, const int* in_sizes, int n_in,
                              void* d_out, int out_size, void* d_ws, size_t ws_size,
                              hipStream_t stream)
{
  const float* x   = (const float*)d_in[0];
  const float* w1  = (const float*)d_in[1];
  const float* b1  = (const float*)d_in[2];
  const float* w2  = (const float*)d_in[3];
  const float* b2  = (const float*)d_in[4];
  const float* fw1 = (const float*)d_in[5];  const float* fb1 = (const float*)d_in[6];
  const float* gw1 = (const float*)d_in[7];  const float* gb1 = (const float*)d_in[8];
  const float* fw2 = (const float*)d_in[9];  const float* fb2 = (const float*)d_in[10];
  const float* gw2 = (const float*)d_in[11]; const float* gb2 = (const float*)d_in[12];
  const float* fw3 = (const float*)d_in[13]; const float* fb3 = (const float*)d_in[14];
  const float* gw3 = (const float*)d_in[15]; const float* gb3 = (const float*)d_in[16];
  const float* wo  = (const float*)d_in[17]; const float* bo  = (const float*)d_in[18];

  float* out = (float*)d_out;
  float* adj = out + (size_t)B_*N_*O_;

  char* ws = (char*)d_ws;
  unsigned short* Ubf  = (unsigned short*)ws;                       // 4 MB
  float* h             = (float*)(ws + (4ull<<20));                 // 2 MB
  float* z0            = (float*)(ws + (6ull<<20));                 // 2 MB
  float* z1            = (float*)(ws + (8ull<<20));                 // 2 MB
  unsigned short* zbT0 = (unsigned short*)(ws + (10ull<<20));       // 1 MB
  unsigned short* zbT1 = (unsigned short*)(ws + (11ull<<20));       // 1 MB
  unsigned short* adjbf= (unsigned short*)(ws + (12ull<<20));       // 32 MB
  bool use_bf = ws_size >= (44ull<<20);

  k_u<<<B_*N_, 128, 0, stream>>>(x, w1, b1, w2, b2, Ubf);
  k_adj<<<B_*16, 512, 0, stream>>>(Ubf, adj, adjbf, use_bf ? 1 : 0);
  k_conv<<<B_*N_/8, 256, 0, stream>>>(x, fw1,fb1,gw1,gb1, fw2,fb2,gw2,gb2, fw3,fb3,gw3,gb3, h, zbT0);

  const float* zi = h;
  const unsigned short* zbi = zbT0;
  float* zfbuf[2] = {z0, z1};
  unsigned short* zbbuf[2] = {zbT1, zbT0};
  for (int it = 0; it < 10; ++it) {
    float* zo = zfbuf[it & 1];
    unsigned short* zbo = zbbuf[it & 1];
    if (use_bf)
      k_propm_bf<<<B_*64, 256, 0, stream>>>(adjbf, zbi, h, zi, zo, zbo);
    else
      k_propm_f32<<<B_*64, 256, 0, stream>>>(adj, zbi, h, zi, zo, zbo);
    zi = zo; zbi = zbo;
  }
  k_out<<<(B_*N_*O_ + 255)/256, 256, 0, stream>>>(zi, wo, bo, out);
}

// Round 7
// 292.980 us; speedup vs baseline: 1.3768x; 1.2858x over previous
//
#include <hip/hip_runtime.h>
#include <hip/hip_bf16.h>
#include <cstddef>

#define B_ 16
#define T_ 64
#define N_ 1024
#define D_ 32
#define H_ 64
#define C_ 32
#define O_ 12

typedef __attribute__((ext_vector_type(8))) short bf16x8;
typedef __attribute__((ext_vector_type(4))) float f32x4;
#define MFMA16(a,b,c) __builtin_amdgcn_mfma_f32_16x16x32_bf16(a,b,c,0,0,0)

__device__ __forceinline__ float d_tanhf(float v){ float e = __expf(2.f*v); return 1.f - 2.f/(e + 1.f); }
__device__ __forceinline__ float d_sigmf(float v){ return 1.f/(1.f + __expf(-v)); }
__device__ __forceinline__ short f2bs(float f){
  __hip_bfloat16 h = __float2bfloat16(f);
  union { __hip_bfloat16 b; short s; } u; u.b = h; return u.s;
}

// ---------------- K1: Ubf[b,n,0:64]=bf16(m1), [64:128]=bf16(m2) ----------------
__global__ __launch_bounds__(128) void k_u(const float* __restrict__ x,
    const float* __restrict__ w1, const float* __restrict__ b1,
    const float* __restrict__ w2, const float* __restrict__ b2,
    unsigned short* __restrict__ Ubf)
{
  int row = blockIdx.x;               // b*N + n
  int b = row >> 10, n = row & (N_-1);
  int t = threadIdx.x;
  int hh = t & (H_-1), which = t >> 6;
  __shared__ float xl[D_];
  if (t < D_) xl[t] = x[(((size_t)b*T_ + (T_-1))*N_ + n)*D_ + t];
  __syncthreads();
  const float* w  = which ? w2 : w1;
  const float* bi = which ? b2 : b1;
  float acc = bi[hh];
  #pragma unroll
  for (int d = 0; d < D_; ++d) acc += xl[d] * w[d*H_ + hh];
  Ubf[(size_t)row*128 + which*H_ + hh] = (unsigned short)f2bs(acc);
}

// ---------------- K2: adj = softmax(tanh(S)) via MFMA; also emits bf16 copy ----------------
__global__ __launch_bounds__(512, 1) void k_adj(const unsigned short* __restrict__ Ubf,
                                                float* __restrict__ adj,
                                                unsigned short* __restrict__ adjbf,
                                                int write_bf)
{
  __shared__ float rsum[2][64];
  int b  = blockIdx.x >> 4;
  int n0 = (blockIdx.x & 15) * 64;
  int tid = threadIdx.x;
  int w = tid >> 6, l = tid & 63;
  int wr = w & 3, wc = w >> 2;
  int l15 = l & 15, lg = l >> 4;
  const unsigned short* Ub = Ubf + (size_t)b*N_*128;

  bf16x8 afr[4];
  #pragma unroll
  for (int kc = 0; kc < 4; ++kc)
    afr[kc] = *reinterpret_cast<const bf16x8*>(Ub + (size_t)(n0 + 16*wr + l15)*128 + 32*kc + 8*lg);

  f32x4 acc[32];
  #pragma unroll
  for (int ct = 0; ct < 32; ++ct) acc[ct] = (f32x4){0.f,0.f,0.f,0.f};

  #pragma unroll
  for (int ct = 0; ct < 32; ++ct) {
    const unsigned short* Um = Ub + (size_t)(512*wc + 16*ct + l15)*128;
    #pragma unroll
    for (int kc = 0; kc < 4; ++kc) {
      int ks = (32*kc + 8*lg + 64) & 127;
      bf16x8 bfr = *reinterpret_cast<const bf16x8*>(Um + ks);
      acc[ct] = MFMA16(afr[kc], bfr, acc[ct]);
    }
  }

  float rs[4] = {0.f,0.f,0.f,0.f};
  #pragma unroll
  for (int ct = 0; ct < 32; ++ct) {
    #pragma unroll
    for (int r = 0; r < 4; ++r) {
      float e = __expf(d_tanhf(acc[ct][r]));
      acc[ct][r] = e;
      rs[r] += e;
    }
  }
  #pragma unroll
  for (int r = 0; r < 4; ++r) {
    float s = rs[r];
    s += __shfl_xor(s, 1); s += __shfl_xor(s, 2);
    s += __shfl_xor(s, 4); s += __shfl_xor(s, 8);
    rs[r] = s;
  }
  if (l15 == 0) {
    #pragma unroll
    for (int r = 0; r < 4; ++r)
      rsum[wc][16*wr + 4*lg + r] = rs[r];
  }
  __syncthreads();
  float inv[4];
  #pragma unroll
  for (int r = 0; r < 4; ++r) {
    int row = 16*wr + 4*lg + r;
    inv[r] = 1.0f / (rsum[0][row] + rsum[1][row]);
  }
  #pragma unroll
  for (int ct = 0; ct < 32; ++ct) {
    #pragma unroll
    for (int r = 0; r < 4; ++r) {
      int n = n0 + 16*wr + 4*lg + r;
      int m = 512*wc + 16*ct + l15;
      float v = acc[ct][r] * inv[r];
      size_t idx = ((size_t)b*N_ + n)*N_ + m;
      adj[idx] = v;
      if (write_bf) adjbf[idx] = (unsigned short)f2bs(v);
    }
  }
}

// ---------------- K3: gated dilated convs, last position -> h (+ bf16 zbT) ----------------
// 256 thr, 8 series. Weights staged per-layer in LDS (coalesced load, padded stride 25 f4).
__global__ __launch_bounds__(256) void k_conv(const float* __restrict__ x,
    const float* __restrict__ fw1,const float* __restrict__ fb1,const float* __restrict__ gw1,const float* __restrict__ gb1,
    const float* __restrict__ fw2,const float* __restrict__ fb2,const float* __restrict__ gw2,const float* __restrict__ gb2,
    const float* __restrict__ fw3,const float* __restrict__ fb3,const float* __restrict__ gw3,const float* __restrict__ gb3,
    float* __restrict__ h, unsigned short* __restrict__ zbT)
{
  __shared__ float xs[8][15][32];    // 15.4 KB
  __shared__ float y1[8][7][32];     //  7.2 KB
  __shared__ float y2[8][3][32];     //  3.1 KB
  __shared__ float4 wl4[1600];       // 25.6 KB: f at [c*25+f4], g at [800 + c*25+f4]
  int tid = threadIdx.x;
  int b  = blockIdx.x >> 7;
  int n0 = (blockIdx.x & 127) * 8;

  // stage x + layer1 weights
  for (int l = tid; l < 960; l += 256) {
    int t = l >> 6, r = l & 63;
    int nl = r >> 3, d4 = r & 7;
    float4 v = reinterpret_cast<const float4*>(x)[(((size_t)b*T_ + 49 + t)*N_ + n0 + nl)*8 + d4];
    *reinterpret_cast<float4*>(&xs[nl][t][d4*4]) = v;
  }
  for (int l = tid; l < 768; l += 256) {
    int c = l / 24, f4 = l - c*24;
    wl4[c*25 + f4]       = reinterpret_cast<const float4*>(fw1)[l];
    wl4[800 + c*25 + f4] = reinterpret_cast<const float4*>(gw1)[l];
  }
  __syncthreads();

  int s = tid >> 5, c = tid & 31;

  // ---- conv1 (dil 1), 7 positions
  float af[7], ag[7];
  {
    float bf = fb1[c], bg = gb1[c];
    #pragma unroll
    for (int p=0;p<7;++p){ af[p]=bf; ag[p]=bg; }
  }
  for (int ic4 = 0; ic4 < 8; ++ic4) {
    float wfl[12], wgl[12];
    {
      const float4* fp = wl4 + c*25 + ic4*3;
      const float4* gp = wl4 + 800 + c*25 + ic4*3;
      #pragma unroll
      for (int q=0;q<3;++q){
        float4 a = fp[q], g = gp[q];
        wfl[q*4+0]=a.x; wfl[q*4+1]=a.y; wfl[q*4+2]=a.z; wfl[q*4+3]=a.w;
        wgl[q*4+0]=g.x; wgl[q*4+1]=g.y; wgl[q*4+2]=g.z; wgl[q*4+3]=g.w;
      }
    }
    #pragma unroll
    for (int p = 0; p < 7; ++p) {
      float4 xa = *reinterpret_cast<const float4*>(&xs[s][2*p+0][ic4*4]);
      float4 xb = *reinterpret_cast<const float4*>(&xs[s][2*p+1][ic4*4]);
      float4 xc = *reinterpret_cast<const float4*>(&xs[s][2*p+2][ic4*4]);
      af[p] += xa.x*wfl[0] + xb.x*wfl[1] + xc.x*wfl[2]
             + xa.y*wfl[3] + xb.y*wfl[4] + xc.y*wfl[5]
             + xa.z*wfl[6] + xb.z*wfl[7] + xc.z*wfl[8]
             + xa.w*wfl[9] + xb.w*wfl[10]+ xc.w*wfl[11];
      ag[p] += xa.x*wgl[0] + xb.x*wgl[1] + xc.x*wgl[2]
             + xa.y*wgl[3] + xb.y*wgl[4] + xc.y*wgl[5]
             + xa.z*wgl[6] + xb.z*wgl[7] + xc.z*wgl[8]
             + xa.w*wgl[9] + xb.w*wgl[10]+ xc.w*wgl[11];
    }
  }
  #pragma unroll
  for (int p=0;p<7;++p) y1[s][p][c] = d_tanhf(af[p]) * d_sigmf(ag[p]);
  __syncthreads();                   // y1 visible + layer1 weight reads done

  for (int l = tid; l < 768; l += 256) {
    int cc = l / 24, f4 = l - cc*24;
    wl4[cc*25 + f4]       = reinterpret_cast<const float4*>(fw2)[l];
    wl4[800 + cc*25 + f4] = reinterpret_cast<const float4*>(gw2)[l];
  }
  __syncthreads();

  // ---- conv2 (dil 2), 3 positions
  float af2[3], ag2[3];
  {
    float bf = fb2[c], bg = gb2[c];
    #pragma unroll
    for (int r=0;r<3;++r){ af2[r]=bf; ag2[r]=bg; }
  }
  for (int ic4 = 0; ic4 < 8; ++ic4) {
    float wfl[12], wgl[12];
    {
      const float4* fp = wl4 + c*25 + ic4*3;
      const float4* gp = wl4 + 800 + c*25 + ic4*3;
      #pragma unroll
      for (int q=0;q<3;++q){
        float4 a = fp[q], g = gp[q];
        wfl[q*4+0]=a.x; wfl[q*4+1]=a.y; wfl[q*4+2]=a.z; wfl[q*4+3]=a.w;
        wgl[q*4+0]=g.x; wgl[q*4+1]=g.y; wgl[q*4+2]=g.z; wgl[q*4+3]=g.w;
      }
    }
    #pragma unroll
    for (int r = 0; r < 3; ++r) {
      float4 xa = *reinterpret_cast<const float4*>(&y1[s][2*r+0][ic4*4]);
      float4 xb = *reinterpret_cast<const float4*>(&y1[s][2*r+1][ic4*4]);
      float4 xc = *reinterpret_cast<const float4*>(&y1[s][2*r+2][ic4*4]);
      af2[r] += xa.x*wfl[0] + xb.x*wfl[1] + xc.x*wfl[2]
              + xa.y*wfl[3] + xb.y*wfl[4] + xc.y*wfl[5]
              + xa.z*wfl[6] + xb.z*wfl[7] + xc.z*wfl[8]
              + xa.w*wfl[9] + xb.w*wfl[10]+ xc.w*wfl[11];
      ag2[r] += xa.x*wgl[0] + xb.x*wgl[1] + xc.x*wgl[2]
              + xa.y*wgl[3] + xb.y*wgl[4] + xc.y*wgl[5]
              + xa.z*wgl[6] + xb.z*wgl[7] + xc.z*wgl[8]
              + xa.w*wgl[9] + xb.w*wgl[10]+ xc.w*wgl[11];
    }
  }
  #pragma unroll
  for (int r=0;r<3;++r) y2[s][r][c] = d_tanhf(af2[r]) * d_sigmf(ag2[r]);
  __syncthreads();                   // y2 visible + layer2 weight reads done

  for (int l = tid; l < 768; l += 256) {
    int cc = l / 24, f4 = l - cc*24;
    wl4[cc*25 + f4]       = reinterpret_cast<const float4*>(fw3)[l];
    wl4[800 + cc*25 + f4] = reinterpret_cast<const float4*>(gw3)[l];
  }
  __syncthreads();

  // ---- conv3 (dil 4), last position
  float af3 = fb3[c], ag3 = gb3[c];
  for (int ic4 = 0; ic4 < 8; ++ic4) {
    float wfl[12], wgl[12];
    {
      const float4* fp = wl4 + c*25 + ic4*3;
      const float4* gp = wl4 + 800 + c*25 + ic4*3;
      #pragma unroll
      for (int q=0;q<3;++q){
        float4 a = fp[q], g = gp[q];
        wfl[q*4+0]=a.x; wfl[q*4+1]=a.y; wfl[q*4+2]=a.z; wfl[q*4+3]=a.w;
        wgl[q*4+0]=g.x; wgl[q*4+1]=g.y; wgl[q*4+2]=g.z; wgl[q*4+3]=g.w;
      }
    }
    float4 xa = *reinterpret_cast<const float4*>(&y2[s][0][ic4*4]);
    float4 xb = *reinterpret_cast<const float4*>(&y2[s][1][ic4*4]);
    float4 xc = *reinterpret_cast<const float4*>(&y2[s][2][ic4*4]);
    af3 += xa.x*wfl[0] + xb.x*wfl[1] + xc.x*wfl[2]
         + xa.y*wfl[3] + xb.y*wfl[4] + xc.y*wfl[5]
         + xa.z*wfl[6] + xb.z*wfl[7] + xc.z*wfl[8]
         + xa.w*wfl[9] + xb.w*wfl[10]+ xc.w*wfl[11];
    ag3 += xa.x*wgl[0] + xb.x*wgl[1] + xc.x*wgl[2]
         + xa.y*wgl[3] + xb.y*wgl[4] + xc.y*wgl[5]
         + xa.z*wgl[6] + xb.z*wgl[7] + xc.z*wgl[8]
         + xa.w*wgl[9] + xb.w*wgl[10]+ xc.w*wgl[11];
  }
  float hv = d_tanhf(af3) * d_sigmf(ag3);
  int n = n0 + s;
  h[((size_t)b*N_ + n)*C_ + c] = hv;
  zbT[((size_t)b*32 + c)*N_ + n] = (unsigned short)f2bs(hv);
}

// ---------------- K4: z' = 0.1h + 0.45z + 0.45 adj@z via MFMA (bf16 adj), 2-way K-split ----------------
__global__ __launch_bounds__(256) void k_propm_bf(const unsigned short* __restrict__ adjbf,
    const unsigned short* __restrict__ zbT, const float* __restrict__ h,
    const float* __restrict__ zin, float* __restrict__ zout,
    unsigned short* __restrict__ zbTout)
{
  __shared__ float red[2][16][17];
  int b = blockIdx.x >> 6;
  int g = blockIdx.x & 63;
  int tid = threadIdx.x;
  int w = tid >> 6, l = tid & 63;
  int wk = w >> 1, wc = w & 1;
  int l15 = l & 15, lg = l >> 4;
  int n_base = g*16;

  const unsigned short* A = adjbf + ((size_t)b*N_ + n_base + l15)*N_ + wk*512;
  const unsigned short* Z = zbT + ((size_t)b*32 + 16*wc + l15)*N_ + wk*512;

  f32x4 acc0 = {0.f,0.f,0.f,0.f}, acc1 = {0.f,0.f,0.f,0.f};
  #pragma unroll
  for (int kc = 0; kc < 16; kc += 2) {
    int k0 = 32*kc + 8*lg;
    bf16x8 a0 = *reinterpret_cast<const bf16x8*>(A + k0);
    bf16x8 z0 = *reinterpret_cast<const bf16x8*>(Z + k0);
    bf16x8 a1 = *reinterpret_cast<const bf16x8*>(A + k0 + 32);
    bf16x8 z1 = *reinterpret_cast<const bf16x8*>(Z + k0 + 32);
    acc0 = MFMA16(a0, z0, acc0);
    acc1 = MFMA16(a1, z1, acc1);
  }
  f32x4 acc = acc0 + acc1;

  if (wk == 1) {
    #pragma unroll
    for (int r = 0; r < 4; ++r) red[wc][4*lg + r][l15] = acc[r];
  }
  __syncthreads();
  if (wk == 0) {
    int c = 16*wc + l15;
    #pragma unroll
    for (int r = 0; r < 4; ++r) {
      float a = acc[r] + red[wc][4*lg + r][l15];
      int n = n_base + 4*lg + r;
      size_t idx = ((size_t)b*N_ + n)*32 + c;
      float v = 0.1f*h[idx] + 0.45f*zin[idx] + 0.45f*a;
      zout[idx] = v;
      zbTout[((size_t)b*32 + c)*N_ + n] = (unsigned short)f2bs(v);
    }
  }
}

// ---------------- K4 fallback: fp32 adj with on-the-fly cvt, 2-way K-split ----------------
__global__ __launch_bounds__(256) void k_propm_f32(const float* __restrict__ adj,
    const unsigned short* __restrict__ zbT, const float* __restrict__ h,
    const float* __restrict__ zin, float* __restrict__ zout,
    unsigned short* __restrict__ zbTout)
{
  __shared__ float red[2][16][17];
  int b = blockIdx.x >> 6;
  int g = blockIdx.x & 63;
  int tid = threadIdx.x;
  int w = tid >> 6, l = tid & 63;
  int wk = w >> 1, wc = w & 1;
  int l15 = l & 15, lg = l >> 4;
  int n_base = g*16;

  const float* A = adj + ((size_t)b*N_ + n_base + l15)*N_ + wk*512;
  const unsigned short* Z = zbT + ((size_t)b*32 + 16*wc + l15)*N_ + wk*512;

  f32x4 acc0 = {0.f,0.f,0.f,0.f}, acc1 = {0.f,0.f,0.f,0.f};
  #pragma unroll
  for (int kc = 0; kc < 16; kc += 2) {
    int k0 = 32*kc + 8*lg;
    f32x4 a0 = *reinterpret_cast<const f32x4*>(A + k0);
    f32x4 a1 = *reinterpret_cast<const f32x4*>(A + k0 + 4);
    f32x4 a2 = *reinterpret_cast<const f32x4*>(A + k0 + 32);
    f32x4 a3 = *reinterpret_cast<const f32x4*>(A + k0 + 36);
    bf16x8 zf0 = *reinterpret_cast<const bf16x8*>(Z + k0);
    bf16x8 zf1 = *reinterpret_cast<const bf16x8*>(Z + k0 + 32);
    bf16x8 af0, af1;
    af0[0]=f2bs(a0[0]); af0[1]=f2bs(a0[1]); af0[2]=f2bs(a0[2]); af0[3]=f2bs(a0[3]);
    af0[4]=f2bs(a1[0]); af0[5]=f2bs(a1[1]); af0[6]=f2bs(a1[2]); af0[7]=f2bs(a1[3]);
    af1[0]=f2bs(a2[0]); af1[1]=f2bs(a2[1]); af1[2]=f2bs(a2[2]); af1[3]=f2bs(a2[3]);
    af1[4]=f2bs(a3[0]); af1[5]=f2bs(a3[1]); af1[6]=f2bs(a3[2]); af1[7]=f2bs(a3[3]);
    acc0 = MFMA16(af0, zf0, acc0);
    acc1 = MFMA16(af1, zf1, acc1);
  }
  f32x4 acc = acc0 + acc1;

  if (wk == 1) {
    #pragma unroll
    for (int r = 0; r < 4; ++r) red[wc][4*lg + r][l15] = acc[r];
  }
  __syncthreads();
  if (wk == 0) {
    int c = 16*wc + l15;
    #pragma unroll
    for (int r = 0; r < 4; ++r) {
      float a = acc[r] + red[wc][4*lg + r][l15];
      int n = n_base + 4*lg + r;
      size_t idx = ((size_t)b*N_ + n)*32 + c;
      float v = 0.1f*h[idx] + 0.45f*zin[idx] + 0.45f*a;
      zout[idx] = v;
      zbTout[((size_t)b*32 + c)*N_ + n] = (unsigned short)f2bs(v);
    }
  }
}

// ---------------- K5: out = relu(z) @ wo + bo ----------------
__global__ __launch_bounds__(256) void k_out(const float* __restrict__ z, const float* __restrict__ wo,
                                             const float* __restrict__ bo, float* __restrict__ out)
{
  int gid = blockIdx.x*256 + threadIdx.x;
  if (gid >= B_*N_*O_) return;
  int o = gid % O_; int row = gid / O_;
  const float* zr = z + (size_t)row*C_;
  float acc = bo[o];
  #pragma unroll
  for (int cc = 0; cc < C_; ++cc) acc += fmaxf(zr[cc], 0.f) * wo[cc*O_ + o];
  out[gid] = acc;
}

extern "C" void kernel_launch(void* const* d_in, const int* in_sizes, int n_in,
                              void* d_out, int out_size, void* d_ws, size_t ws_size,
                              hipStream_t stream)
{
  const float* x   = (const float*)d_in[0];
  const float* w1  = (const float*)d_in[1];
  const float* b1  = (const float*)d_in[2];
  const float* w2  = (const float*)d_in[3];
  const float* b2  = (const float*)d_in[4];
  const float* fw1 = (const float*)d_in[5];  const float* fb1 = (const float*)d_in[6];
  const float* gw1 = (const float*)d_in[7];  const float* gb1 = (const float*)d_in[8];
  const float* fw2 = (const float*)d_in[9];  const float* fb2 = (const float*)d_in[10];
  const float* gw2 = (const float*)d_in[11]; const float* gb2 = (const float*)d_in[12];
  const float* fw3 = (const float*)d_in[13]; const float* fb3 = (const float*)d_in[14];
  const float* gw3 = (const float*)d_in[15]; const float* gb3 = (const float*)d_in[16];
  const float* wo  = (const float*)d_in[17]; const float* bo  = (const float*)d_in[18];

  float* out = (float*)d_out;
  float* adj = out + (size_t)B_*N_*O_;

  char* ws = (char*)d_ws;
  unsigned short* Ubf  = (unsigned short*)ws;                       // 4 MB
  float* h             = (float*)(ws + (4ull<<20));                 // 2 MB
  float* z0            = (float*)(ws + (6ull<<20));                 // 2 MB
  float* z1            = (float*)(ws + (8ull<<20));                 // 2 MB
  unsigned short* zbT0 = (unsigned short*)(ws + (10ull<<20));       // 1 MB
  unsigned short* zbT1 = (unsigned short*)(ws + (11ull<<20));       // 1 MB
  unsigned short* adjbf= (unsigned short*)(ws + (12ull<<20));       // 32 MB
  bool use_bf = ws_size >= (44ull<<20);

  k_u<<<B_*N_, 128, 0, stream>>>(x, w1, b1, w2, b2, Ubf);
  k_adj<<<B_*16, 512, 0, stream>>>(Ubf, adj, adjbf, use_bf ? 1 : 0);
  k_conv<<<B_*N_/8, 256, 0, stream>>>(x, fw1,fb1,gw1,gb1, fw2,fb2,gw2,gb2, fw3,fb3,gw3,gb3, h, zbT0);

  const float* zi = h;
  const unsigned short* zbi = zbT0;
  float* zfbuf[2] = {z0, z1};
  unsigned short* zbbuf[2] = {zbT1, zbT0};
  for (int it = 0; it < 10; ++it) {
    float* zo = zfbuf[it & 1];
    unsigned short* zbo = zbbuf[it & 1];
    if (use_bf)
      k_propm_bf<<<B_*64, 256, 0, stream>>>(adjbf, zbi, h, zi, zo, zbo);
    else
      k_propm_f32<<<B_*64, 256, 0, stream>>>(adj, zbi, h, zi, zo, zbo);
    zi = zo; zbi = zbo;
  }
  k_out<<<(B_*N_*O_ + 255)/256, 256, 0, stream>>>(zi, wo, bo, out);
}